// Round 1
// baseline (337.160 us; speedup 1.0000x reference)
//
#include <hip/hip_runtime.h>
#include <hip/hip_bf16.h>
#include <math.h>

// Problem constants
// x: (2, 192, 256, 256) f32 ; w_qkv: (192, 576) ; b_qkv: (576,)
// windows: 32x32 = 1024 per batch, 8x8=64 pixels each
// out: (2, 1024, 4, 64, 192) f32
#define NB   2
#define NC   192
#define HW   256
#define NWIN 1024
#define SHW  64
#define NDQ  192   // qk dim
#define WCOL 576

// ---------------- K1: window mean of x -> xmean[b][n][c] ----------------
__global__ __launch_bounds__(256) void k1_mean(const float* __restrict__ x,
                                               float* __restrict__ xmean) {
  int id = blockIdx.x * 256 + threadIdx.x;      // 2*192*1024 threads
  int n  = id & 1023;
  int c  = (id >> 10) % NC;
  int b  = id / (NC * NWIN);
  int wh = n >> 5, ww = n & 31;
  const float* p = x + (((size_t)(b * NC + c) * HW + wh * 8) * HW + ww * 8);
  double s = 0.0;
#pragma unroll
  for (int r = 0; r < 8; ++r) {
    float4 a = *(const float4*)(p + r * HW);
    float4 q = *(const float4*)(p + r * HW + 4);
    s += (double)a.x + a.y + a.z + a.w + q.x + q.y + q.z + q.w;
  }
  xmean[(size_t)(b * NWIN + n) * NC + c] = (float)(s * (1.0 / 64.0));
}

// ---------------- K2: q_win (scaled) and k_win^T ----------------
// qw[b][n][d] = ((xmean row) . w[:,d] + bias[d]) * scale
// kwT[b][d][n] = (xmean row) . w[:,192+d] + bias[192+d]
__global__ __launch_bounds__(192) void k2_qk(const float* __restrict__ xmean,
                                             const float* __restrict__ w,
                                             const float* __restrict__ bias,
                                             float* __restrict__ qw,
                                             float* __restrict__ kwT) {
  int b = blockIdx.y, n = blockIdx.x;
  int d = threadIdx.x;  // 192 threads
  __shared__ float xs[NC];
  xs[d] = xmean[(size_t)(b * NWIN + n) * NC + d];
  __syncthreads();
  double aq = 0.0, ak = 0.0;
  for (int c = 0; c < NC; ++c) {
    double xc = (double)xs[c];
    aq += xc * (double)w[c * WCOL + d];
    ak += xc * (double)w[c * WCOL + NDQ + d];
  }
  const float scale = 0.0721687836487032f;  // 192^-0.5 (f32)
  float qv = (float)aq + bias[d];
  float kv = (float)ak + bias[NDQ + d];
  qw[(size_t)(b * NWIN + n) * NC + d] = qv * scale;
  kwT[(size_t)b * NC * NWIN + (size_t)d * NWIN + n] = kv;
}

// ---------------- K3: logits row + top-4 (+ counts) ----------------
__global__ __launch_bounds__(256) void k3_topk(const float* __restrict__ qw,
                                               const float* __restrict__ kwT,
                                               int* __restrict__ topk,
                                               int* __restrict__ counts) {
  int b = blockIdx.y, n = blockIdx.x;
  int tid = threadIdx.x;
  __shared__ float qs[NC];
  __shared__ float rv[256];
  __shared__ int   ri[256];
  __shared__ int   wini;
  if (tid < NC) qs[tid] = qw[(size_t)(b * NWIN + n) * NC + tid];
  __syncthreads();

  const float* kb = kwT + (size_t)b * NC * NWIN;
  double acc0 = 0, acc1 = 0, acc2 = 0, acc3 = 0;
  for (int c = 0; c < NC; ++c) {
    float4 kv = *(const float4*)(kb + (size_t)c * NWIN + tid * 4);
    double q = (double)qs[c];
    acc0 += q * (double)kv.x;
    acc1 += q * (double)kv.y;
    acc2 += q * (double)kv.z;
    acc3 += q * (double)kv.w;
  }
  float val[4];
  int   midx[4];
  val[0] = (float)acc0; val[1] = (float)acc1;
  val[2] = (float)acc2; val[3] = (float)acc3;
#pragma unroll
  for (int i = 0; i < 4; ++i) midx[i] = tid * 4 + i;

  for (int r = 0; r < 4; ++r) {
    float bv = -INFINITY; int bi = 0x7fffffff;
#pragma unroll
    for (int i = 0; i < 4; ++i) {
      if (val[i] > bv || (val[i] == bv && midx[i] < bi)) { bv = val[i]; bi = midx[i]; }
    }
    rv[tid] = bv; ri[tid] = bi;
    __syncthreads();
    for (int s = 128; s > 0; s >>= 1) {
      if (tid < s) {
        float ov = rv[tid + s]; int oi = ri[tid + s];
        if (ov > rv[tid] || (ov == rv[tid] && oi < ri[tid])) { rv[tid] = ov; ri[tid] = oi; }
      }
      __syncthreads();
    }
    if (tid == 0) {
      wini = ri[0];
      topk[(size_t)(b * NWIN + n) * 4 + r] = ri[0];
      atomicAdd(&counts[b * NWIN + ri[0]], 1);
    }
    __syncthreads();
    int wi = wini;
#pragma unroll
    for (int i = 0; i < 4; ++i) if (midx[i] == wi) val[i] = -INFINITY;
    __syncthreads();
  }
}

// ---------------- K_scan: exclusive scan of counts -> offsets, cursor ----------------
__global__ __launch_bounds__(1024) void k_scan(const int* __restrict__ counts,
                                               int* __restrict__ offs,
                                               int* __restrict__ cursor) {
  int b = blockIdx.x;
  int t = threadIdx.x;
  __shared__ int sd[1024];
  int v = counts[b * NWIN + t];
  sd[t] = v;
  __syncthreads();
  for (int s = 1; s < 1024; s <<= 1) {
    int add = (t >= s) ? sd[t - s] : 0;
    __syncthreads();
    sd[t] += add;
    __syncthreads();
  }
  int excl = sd[t] - v;
  offs[b * NWIN + t]   = excl;
  cursor[b * NWIN + t] = excl;
}

// ---------------- K_fill: build selector lists ----------------
__global__ __launch_bounds__(256) void k_fill(const int* __restrict__ topk,
                                              int* __restrict__ cursor,
                                              int* __restrict__ list) {
  int id = blockIdx.x * 256 + threadIdx.x;   // 2*1024*4
  int b   = id >> 12;
  int rem = id & 4095;                       // n*4 + k
  int m   = topk[b * 4096 + rem];
  int pos = atomicAdd(&cursor[b * NWIN + m], 1);
  list[b * 4096 + pos] = rem;
}

// ---------------- K4: compute V tile for window m, scatter to selectors ----------------
__global__ __launch_bounds__(256) void k4_scatter(const float* __restrict__ x,
                                                  const float* __restrict__ w,
                                                  const float* __restrict__ bias,
                                                  const int* __restrict__ counts,
                                                  const int* __restrict__ offs,
                                                  const int* __restrict__ list,
                                                  float* __restrict__ out) {
  int b = blockIdx.y, m = blockIdx.x;
  int cnt = counts[b * NWIN + m];
  if (cnt == 0) return;
  int tid = threadIdx.x;
  int wh = m >> 5, ww = m & 31;

  __shared__ float buf[12288];  // xs[c][p] during GEMM, then v[p][d]

  // load x window: buf[c*64 + p]
  const float* xb = x + ((size_t)b * NC * HW * HW) + (size_t)(wh * 8) * HW + ww * 8;
#pragma unroll
  for (int i = 0; i < 12; ++i) {
    int l = tid + i * 256;          // over 3072 float4
    int c  = l >> 4;
    int pq = l & 15;
    int p0 = pq * 4;
    int row = p0 >> 3, col = p0 & 7;
    float4 vx = *(const float4*)(xb + (size_t)c * HW * HW + row * HW + col);
    *(float4*)&buf[c * 64 + p0] = vx;
  }
  __syncthreads();

  // register-tiled GEMM: 16x16 threads, each 4 pixels x 12 dims
  int tx = tid & 15, tg = tid >> 4;
  int p0 = tx * 4, d0 = tg * 12;
  float acc[4][12];
  float bv[12];
#pragma unroll
  for (int j = 0; j < 12; ++j) bv[j] = bias[384 + d0 + j];
#pragma unroll
  for (int pi = 0; pi < 4; ++pi)
#pragma unroll
    for (int j = 0; j < 12; ++j) acc[pi][j] = bv[j];

  const float* wv = w + 384 + d0;
  for (int c = 0; c < NC; ++c) {
    float4 xv = *(const float4*)&buf[c * 64 + p0];
    const float* wr = wv + c * WCOL;
    float4 w0 = *(const float4*)(wr);
    float4 w1 = *(const float4*)(wr + 4);
    float4 w2 = *(const float4*)(wr + 8);
    float wf[12] = {w0.x, w0.y, w0.z, w0.w, w1.x, w1.y, w1.z, w1.w, w2.x, w2.y, w2.z, w2.w};
    float xf[4] = {xv.x, xv.y, xv.z, xv.w};
#pragma unroll
    for (int pi = 0; pi < 4; ++pi)
#pragma unroll
      for (int j = 0; j < 12; ++j) acc[pi][j] = fmaf(xf[pi], wf[j], acc[pi][j]);
  }
  __syncthreads();

  // write tile to LDS in [p][d] layout
#pragma unroll
  for (int pi = 0; pi < 4; ++pi) {
#pragma unroll
    for (int g = 0; g < 3; ++g) {
      *(float4*)&buf[(p0 + pi) * NC + d0 + 4 * g] =
          make_float4(acc[pi][4 * g], acc[pi][4 * g + 1], acc[pi][4 * g + 2], acc[pi][4 * g + 3]);
    }
  }
  __syncthreads();

  // scatter to every selecting output slot
  int off = offs[b * NWIN + m];
  const float4* bf4 = (const float4*)buf;
  for (int s = 0; s < cnt; ++s) {
    int sel = list[b * 4096 + off + s];
    int n_sel = sel >> 2, k = sel & 3;
    float4* dst4 = (float4*)(out + (((size_t)(b * NWIN + n_sel) * 4 + k) * SHW) * NC);
#pragma unroll
    for (int i = 0; i < 12; ++i) {
      int j = tid + i * 256;
      dst4[j] = bf4[j];
    }
  }
}

extern "C" void kernel_launch(void* const* d_in, const int* in_sizes, int n_in,
                              void* d_out, int out_size, void* d_ws, size_t ws_size,
                              hipStream_t stream) {
  const float* x    = (const float*)d_in[0];
  const float* w    = (const float*)d_in[1];
  const float* bias = (const float*)d_in[2];
  float* out = (float*)d_out;

  float* xmean = (float*)d_ws;                 // 2*1024*192
  float* qw    = xmean + 393216;               // 2*1024*192
  float* kwT   = qw + 393216;                  // 2*192*1024
  int*   topk   = (int*)(kwT + 393216);        // 2*1024*4
  int*   counts = topk + 8192;                 // 2*1024
  int*   offs   = counts + 2048;               // 2*1024
  int*   cursor = offs + 2048;                 // 2*1024
  int*   list   = cursor + 2048;               // 2*4096

  hipMemsetAsync(counts, 0, 2048 * sizeof(int), stream);
  k1_mean<<<1536, 256, 0, stream>>>(x, xmean);
  k2_qk<<<dim3(1024, 2), 192, 0, stream>>>(xmean, w, bias, qw, kwT);
  k3_topk<<<dim3(1024, 2), 256, 0, stream>>>(qw, kwT, topk, counts);
  k_scan<<<2, 1024, 0, stream>>>(counts, offs, cursor);
  k_fill<<<32, 256, 0, stream>>>(topk, cursor, list);
  k4_scatter<<<dim3(1024, 2), 256, 0, stream>>>(x, w, bias, counts, offs, list, out);
}